// Round 6
// baseline (310.937 us; speedup 1.0000x reference)
//
#include <hip/hip_runtime.h>

#define NN 2048
#define BB 16
#define TT 256

typedef unsigned short ushort_t;
typedef short bf16x8 __attribute__((ext_vector_type(8)));
typedef float f32x4 __attribute__((ext_vector_type(4)));

__device__ __forceinline__ ushort_t f2bf(float f) {
    unsigned u = __float_as_uint(f);
    return (ushort_t)((u + 0x7FFFu + ((u >> 16) & 1u)) >> 16);  // RNE
}

// async global->LDS, 16B per lane; LDS dest must be wave-uniform-base + lane*16
__device__ __forceinline__ void gload16(const void* g, void* l) {
    __builtin_amdgcn_global_load_lds((const __attribute__((address_space(1))) unsigned int*)g,
                                     (__attribute__((address_space(3))) unsigned int*)l,
                                     16, 0, 0);
}

// Shared 128x128-tile bf16 MFMA main loop, double-buffered LDS, 2-phase:
// stage(next) issued BEFORE compute(cur); single __syncthreads per K-step
// (its vmcnt(0) drain waits on loads whose latency hid under this step's MFMA).
__device__ __forceinline__ void mfma_loop128(
    const ushort_t* __restrict__ Ag, size_t lda,
    const ushort_t* __restrict__ Bg, size_t ldb,
    int m0, int n0, int nkt,
    ushort_t (*As)[128][32], ushort_t (*Bs)[128][32],
    f32x4 (&acc)[4][4], int tid)
{
    const int lane = tid & 63, wave = tid >> 6;
    const int wr = wave >> 1, wc = wave & 1;
    const int r0 = tid >> 2, kc = (tid & 3) * 8;
    const int lr = lane & 15, kg = (lane >> 4) * 8;
    // prologue: stage K-tile 0 into buffer 0
    gload16(&Ag[(size_t)(m0 + r0) * lda + kc], &As[0][r0][kc]);
    gload16(&Bg[(size_t)(n0 + r0) * ldb + kc], &Bs[0][r0][kc]);
    gload16(&Ag[(size_t)(m0 + r0 + 64) * lda + kc], &As[0][r0 + 64][kc]);
    gload16(&Bg[(size_t)(n0 + r0 + 64) * ldb + kc], &Bs[0][r0 + 64][kc]);
    __syncthreads();
    int cur = 0;
    for (int kt = 0; kt < nkt; kt++) {
        if (kt + 1 < nkt) {  // issue next-tile loads into the other buffer
            const int k0 = (kt + 1) * 32;
            gload16(&Ag[(size_t)(m0 + r0) * lda + k0 + kc], &As[cur ^ 1][r0][kc]);
            gload16(&Bg[(size_t)(n0 + r0) * ldb + k0 + kc], &Bs[cur ^ 1][r0][kc]);
            gload16(&Ag[(size_t)(m0 + r0 + 64) * lda + k0 + kc], &As[cur ^ 1][r0 + 64][kc]);
            gload16(&Bg[(size_t)(n0 + r0 + 64) * ldb + k0 + kc], &Bs[cur ^ 1][r0 + 64][kc]);
        }
        bf16x8 af[4], bf[4];
#pragma unroll
        for (int f = 0; f < 4; f++) {
            af[f] = *(const bf16x8*)&As[cur][wr * 64 + f * 16 + lr][kg];
            bf[f] = *(const bf16x8*)&Bs[cur][wc * 64 + f * 16 + lr][kg];
        }
#pragma unroll
        for (int i = 0; i < 4; i++)
#pragma unroll
            for (int j = 0; j < 4; j++)
                acc[i][j] = __builtin_amdgcn_mfma_f32_16x16x32_bf16(af[i], bf[j], acc[i][j], 0, 0, 0);
        __syncthreads();
        cur ^= 1;
    }
}

// K1: xsumT[t][n] = sum_b x[b][t][n]; also ssq[n] += s^2 (for inv_norm)
__global__ __launch_bounds__(256) void k_colsum(const float* __restrict__ x,
                                                float* __restrict__ xsumT,
                                                float* __restrict__ ssq) {
    const int n = blockIdx.x * 256 + threadIdx.x;
    const int t = blockIdx.y;
    float s = 0.f;
#pragma unroll
    for (int b = 0; b < BB; b++) s += x[(size_t)(b * TT + t) * NN + n];
    xsumT[(size_t)t * NN + n] = s;
    atomicAdd(&ssq[n], s * s);
}

// K2: sim GEMM (fp32, K=256, 64x64 tile, dbuf 2-phase) + gumbel comparator -> adjb
__global__ __launch_bounds__(256) void k_adj(const float* __restrict__ A,
                                             const float* __restrict__ ssq,
                                             const float* __restrict__ gumbel,
                                             ushort_t* __restrict__ adjb) {
    __shared__ __align__(16) float As[2][32][64];
    __shared__ __align__(16) float Bs[2][32][64];
    const int m0 = blockIdx.y * 64, n0 = blockIdx.x * 64;
    const int tid = threadIdx.x;
    const int tx = tid & 15, ty = tid >> 4;
    const int sr = tid >> 4, sc = (tid & 15) * 4;  // staging coords
    float acc[4][4];
#pragma unroll
    for (int i = 0; i < 4; i++)
#pragma unroll
        for (int j = 0; j < 4; j++) acc[i][j] = 0.f;
    // prologue
    gload16(&A[(size_t)sr * NN + m0 + sc], &As[0][sr][sc]);
    gload16(&A[(size_t)sr * NN + n0 + sc], &Bs[0][sr][sc]);
    gload16(&A[(size_t)(sr + 16) * NN + m0 + sc], &As[0][sr + 16][sc]);
    gload16(&A[(size_t)(sr + 16) * NN + n0 + sc], &Bs[0][sr + 16][sc]);
    __syncthreads();
    int cur = 0;
    for (int kt = 0; kt < 8; kt++) {
        if (kt + 1 < 8) {
            const int k0 = (kt + 1) * 32;
            gload16(&A[(size_t)(k0 + sr) * NN + m0 + sc], &As[cur ^ 1][sr][sc]);
            gload16(&A[(size_t)(k0 + sr) * NN + n0 + sc], &Bs[cur ^ 1][sr][sc]);
            gload16(&A[(size_t)(k0 + sr + 16) * NN + m0 + sc], &As[cur ^ 1][sr + 16][sc]);
            gload16(&A[(size_t)(k0 + sr + 16) * NN + n0 + sc], &Bs[cur ^ 1][sr + 16][sc]);
        }
#pragma unroll 16
        for (int kk = 0; kk < 32; kk++) {
            float4 a = *(const float4*)&As[cur][kk][ty * 4];
            float4 b = *(const float4*)&Bs[cur][kk][tx * 4];
            const float av[4] = {a.x, a.y, a.z, a.w};
            const float bv[4] = {b.x, b.y, b.z, b.w};
#pragma unroll
            for (int i = 0; i < 4; i++)
#pragma unroll
                for (int j = 0; j < 4; j++) acc[i][j] = fmaf(av[i], bv[j], acc[i][j]);
        }
        __syncthreads();
        cur ^= 1;
    }
    float invi[4], invj[4];
#pragma unroll
    for (int i = 0; i < 4; i++) {
        const float si = ssq[m0 + ty * 4 + i];
        invi[i] = (si > 0.f) ? rsqrtf(si) : 0.f;
        const float sj = ssq[n0 + tx * 4 + i];
        invj[i] = (sj > 0.f) ? rsqrtf(sj) : 0.f;
    }
#pragma unroll
    for (int i = 0; i < 4; i++) {
        const int gi = m0 + ty * 4 + i;
        const size_t rowb = (size_t)gi * NN + n0 + tx * 4;
#pragma unroll
        for (int j = 0; j < 4; j++) {
            const float dot = acc[i][j] * invi[i] * invj[j];
            const float2 g = *(const float2*)&gumbel[2 * (rowb + j)];
            adjb[rowb + j] = (dot > g.y - g.x) ? (ushort_t)0x3F80 : (ushort_t)0;
        }
    }
}

// K3: nmask = adj | adjT | I  as bf16 (exact 0/1)
__global__ __launch_bounds__(256) void k_nmask(const ushort_t* __restrict__ adjb,
                                               ushort_t* __restrict__ nm) {
    __shared__ ushort_t tt[32][33];
    const int J = blockIdx.x * 32, I = blockIdx.y * 32;
    const int c = threadIdx.x & 31, r0 = threadIdx.x >> 5;  // 8 row-groups
#pragma unroll
    for (int r = r0; r < 32; r += 8) tt[r][c] = adjb[(size_t)(J + r) * NN + I + c];
    __syncthreads();
#pragma unroll
    for (int r = r0; r < 32; r += 8) {
        const int gi = I + r, gj = J + c;
        const bool on = (gi == gj) || adjb[(size_t)gi * NN + gj] || tt[c][r];
        nm[(size_t)gi * NN + gj] = on ? (ushort_t)0x3F80 : (ushort_t)0;
    }
}

// K4: common = nmask @ nmask (bf16 MFMA, integer-exact), fused
//     W[i][j] = adj * (common>1) * common^2   (max_common cancels in Wn)
//     + deg[j] partial sums via atomicAdd (deg zeroed beforehand)
__global__ __launch_bounds__(256) void k_commonW(const ushort_t* __restrict__ nm,
                                                 const ushort_t* __restrict__ adjb,
                                                 float* __restrict__ W,
                                                 float* __restrict__ deg) {
    __shared__ __align__(16) ushort_t As[2][128][32];
    __shared__ __align__(16) ushort_t Bs[2][128][32];
    const int m0 = blockIdx.y * 128, n0 = blockIdx.x * 128;
    const int tid = threadIdx.x;
    const int lane = tid & 63, wave = tid >> 6;
    const int wr = wave >> 1, wc = wave & 1;
    f32x4 acc[4][4];
#pragma unroll
    for (int i = 0; i < 4; i++)
#pragma unroll
        for (int j = 0; j < 4; j++) acc[i][j] = (f32x4){0.f, 0.f, 0.f, 0.f};
    mfma_loop128(nm, NN, nm, NN, m0, n0, NN / 32, As, Bs, acc, tid);
    const int lr = lane & 15, rg = (lane >> 4) * 4;
#pragma unroll
    for (int j = 0; j < 4; j++) {
        const int gj = n0 + wc * 64 + j * 16 + lr;
        float psum = 0.f;
#pragma unroll
        for (int i = 0; i < 4; i++)
#pragma unroll
            for (int r = 0; r < 4; r++) {
                const int gi = m0 + wr * 64 + i * 16 + rg + r;
                const float cv = acc[i][j][r];
                const size_t fl = (size_t)gi * NN + gj;
                const float wv = (cv > 1.0f && adjb[fl]) ? cv * cv : 0.f;
                W[fl] = wv;
                psum += wv;
            }
        atomicAdd(&deg[gj], psum);
    }
}

// K5: Wtn[d][s] = bf16( dinv[s] * W[s][d] * dinv[d] ), dinv computed inline from deg
__global__ __launch_bounds__(256) void k_wtn(const float* __restrict__ W,
                                             const float* __restrict__ deg,
                                             ushort_t* __restrict__ Wtn) {
    __shared__ float tt[64][65];
    const int S0 = blockIdx.x * 64, D0 = blockIdx.y * 64;
    const int c = threadIdx.x & 63, r0 = threadIdx.x >> 6;  // 4 row-groups
#pragma unroll
    for (int r = r0; r < 64; r += 4) tt[r][c] = W[(size_t)(S0 + r) * NN + D0 + c];
    __syncthreads();
    const float dgs = deg[S0 + c];
    const float ds = (dgs > 0.f) ? rsqrtf(dgs) : 0.f;
#pragma unroll
    for (int r = r0; r < 64; r += 4) {
        const int d = D0 + r;
        const float dgd = deg[d];
        const float dd = (dgd > 0.f) ? rsqrtf(dgd) : 0.f;
        Wtn[(size_t)d * NN + S0 + c] = f2bf(tt[c][r] * ds * dd);
    }
}

// K6: transpose+convert x[b][t][n] fp32 -> xT[b][n][t] bf16
__global__ __launch_bounds__(256) void k_xt(const float* __restrict__ x,
                                            ushort_t* __restrict__ xT) {
    __shared__ float tile[64][65];
    const int b = blockIdx.z, t0 = blockIdx.y * 64, n0 = blockIdx.x * 64;
    const int c = threadIdx.x & 63, r0 = threadIdx.x >> 6;
#pragma unroll
    for (int r = r0; r < 64; r += 4)
        tile[r][c] = x[(size_t)(b * TT + t0 + r) * NN + n0 + c];
    __syncthreads();
#pragma unroll
    for (int r = r0; r < 64; r += 4)
        xT[(size_t)(b * NN + n0 + r) * TT + t0 + c] = f2bf(tile[c][r]);
}

// K7: wT[o][t] = bf16(w[t][o])
__global__ __launch_bounds__(256) void k_wt(const float* __restrict__ w,
                                            ushort_t* __restrict__ wT) {
    __shared__ float tile[64][65];
    const int t0 = blockIdx.y * 64, o0 = blockIdx.x * 64;
    const int c = threadIdx.x & 63, r0 = threadIdx.x >> 6;
#pragma unroll
    for (int r = r0; r < 64; r += 4)
        tile[r][c] = w[(size_t)(t0 + r) * TT + o0 + c];
    __syncthreads();
#pragma unroll
    for (int r = r0; r < 64; r += 4)
        wT[(size_t)(o0 + r) * TT + t0 + c] = f2bf(tile[c][r]);
}

// K8: xwT[b][o][n] = sum_t wT[o][t] * xT[b][n][t]  (bf16 MFMA), stored bf16
__global__ __launch_bounds__(256) void k_xw(const ushort_t* __restrict__ wT,
                                            const ushort_t* __restrict__ xT,
                                            ushort_t* __restrict__ xwT) {
    __shared__ __align__(16) ushort_t As[2][128][32];
    __shared__ __align__(16) ushort_t Bs[2][128][32];
    const int b = blockIdx.z;
    const ushort_t* __restrict__ Bg = xT + (size_t)b * NN * TT;
    const int m0 = blockIdx.y * 128, n0 = blockIdx.x * 128;
    const int tid = threadIdx.x;
    const int lane = tid & 63, wave = tid >> 6;
    const int wr = wave >> 1, wc = wave & 1;
    f32x4 acc[4][4];
#pragma unroll
    for (int i = 0; i < 4; i++)
#pragma unroll
        for (int j = 0; j < 4; j++) acc[i][j] = (f32x4){0.f, 0.f, 0.f, 0.f};
    mfma_loop128(wT, TT, Bg, TT, m0, n0, TT / 32, As, Bs, acc, tid);
    const int lr = lane & 15, rg = (lane >> 4) * 4;
#pragma unroll
    for (int i = 0; i < 4; i++)
#pragma unroll
        for (int j = 0; j < 4; j++)
#pragma unroll
            for (int r = 0; r < 4; r++) {
                const int o = m0 + wr * 64 + i * 16 + rg + r;
                const int n = n0 + wc * 64 + j * 16 + lr;
                xwT[((size_t)b * TT + o) * NN + n] = f2bf(acc[i][j][r]);
            }
}

// K9: out[bt][d] = sum_s xwT[bt][s] * Wtn[d][s] + bias[bt%T]  (bf16 MFMA)
__global__ __launch_bounds__(256) void k_out(const ushort_t* __restrict__ xwT,
                                             const ushort_t* __restrict__ Wtn,
                                             const float* __restrict__ bias,
                                             float* __restrict__ out) {
    __shared__ __align__(16) ushort_t As[2][128][32];
    __shared__ __align__(16) ushort_t Bs[2][128][32];
    const int m0 = blockIdx.y * 128, n0 = blockIdx.x * 128;
    const int tid = threadIdx.x;
    const int lane = tid & 63, wave = tid >> 6;
    const int wr = wave >> 1, wc = wave & 1;
    f32x4 acc[4][4];
#pragma unroll
    for (int i = 0; i < 4; i++)
#pragma unroll
        for (int j = 0; j < 4; j++) acc[i][j] = (f32x4){0.f, 0.f, 0.f, 0.f};
    mfma_loop128(xwT, NN, Wtn, NN, m0, n0, NN / 32, As, Bs, acc, tid);
    const int lr = lane & 15, rg = (lane >> 4) * 4;
#pragma unroll
    for (int i = 0; i < 4; i++)
#pragma unroll
        for (int j = 0; j < 4; j++)
#pragma unroll
            for (int r = 0; r < 4; r++) {
                const int gm = m0 + wr * 64 + i * 16 + rg + r;  // bt
                const int gd = n0 + wc * 64 + j * 16 + lr;      // node d
                out[(size_t)gm * NN + gd] = acc[i][j][r] + bias[gm & (TT - 1)];
            }
}

extern "C" void kernel_launch(void* const* d_in, const int* in_sizes, int n_in,
                              void* d_out, int out_size, void* d_ws, size_t ws_size,
                              hipStream_t stream) {
    const float* x      = (const float*)d_in[0];
    const float* w      = (const float*)d_in[1];
    const float* bias   = (const float*)d_in[2];
    const float* gumbel = (const float*)d_in[3];
    float* out = (float*)d_out;

    char* ws = (char*)d_ws;
    // layout (bytes); xT aliases adjb+nm (dead after k_commonW); xwT aliases W (dead after k_wtn)
    float*    xsumT = (float*)(ws + 0);              //  2 MB [T][N] f32
    float*    ssq   = (float*)(ws + 2097152);        //  8 KB [N]
    float*    deg   = (float*)(ws + 2105344);        //  8 KB [N]
    ushort_t* adjb  = (ushort_t*)(ws + 2113536);     //  8 MB [N][N] bf16
    ushort_t* nm    = (ushort_t*)(ws + 10502144);    //  8 MB [N][N] bf16
    ushort_t* xT    = (ushort_t*)(ws + 2113536);     // 16 MB [B][N][T] bf16 (aliases adjb+nm)
    float*    W     = (float*)(ws + 18890752);       // 16 MB [N][N] f32
    ushort_t* xwT   = (ushort_t*)(ws + 18890752);    // 16 MB [B*T][N] bf16 (aliases W)
    ushort_t* Wtn   = (ushort_t*)(ws + 35667968);    //  8 MB [N][N] bf16 (transposed Wn)
    ushort_t* wT    = (ushort_t*)(ws + 44056576);    // 128 KB [T][T] bf16

    hipMemsetAsync(ws + 2097152, 0, 16384, stream);  // zero ssq + deg

    k_colsum <<<dim3(NN / 256, TT), 256, 0, stream>>>(x, xsumT, ssq);
    k_adj    <<<dim3(32, 32),       256, 0, stream>>>(xsumT, ssq, gumbel, adjb);
    k_nmask  <<<dim3(64, 64),       256, 0, stream>>>(adjb, nm);
    k_commonW<<<dim3(16, 16),       256, 0, stream>>>(nm, adjb, W, deg);
    k_wtn    <<<dim3(32, 32),       256, 0, stream>>>(W, deg, Wtn);
    k_xt     <<<dim3(32, 4, BB),    256, 0, stream>>>(x, xT);
    k_wt     <<<dim3(4, 4),         256, 0, stream>>>(w, wT);
    k_xw     <<<dim3(16, 2, BB),    256, 0, stream>>>(wT, xT, xwT);
    k_out    <<<dim3(16, 32),       256, 0, stream>>>(xwT, Wtn, bias, out);
}

// Round 7
// 281.290 us; speedup vs baseline: 1.1054x; 1.1054x over previous
//
#include <hip/hip_runtime.h>

#define NN 2048
#define BB 16
#define TT 256

typedef unsigned short ushort_t;
typedef unsigned char u8;
typedef short bf16x8 __attribute__((ext_vector_type(8)));
typedef float f32x4 __attribute__((ext_vector_type(4)));
typedef int i32x4 __attribute__((ext_vector_type(4)));

__device__ __forceinline__ ushort_t f2bf(float f) {
    unsigned u = __float_as_uint(f);
    return (ushort_t)((u + 0x7FFFu + ((u >> 16) & 1u)) >> 16);  // RNE
}

// async global->LDS, 16B per lane; LDS dest must be wave-uniform-base + lane*16
__device__ __forceinline__ void gload16(const void* g, void* l) {
    __builtin_amdgcn_global_load_lds((const __attribute__((address_space(1))) unsigned int*)g,
                                     (__attribute__((address_space(3))) unsigned int*)l,
                                     16, 0, 0);
}

// ---- 128(M)x64(N)-tile bf16 MFMA loop, BK=32, dbuf. 4 waves as 2x2; wave-tile 64x32.
__device__ __forceinline__ void loop_bf16_128x64(
    const ushort_t* __restrict__ Ag, size_t lda,
    const ushort_t* __restrict__ Bg, size_t ldb,
    int m0, int n0, int nkt,
    ushort_t (*As)[128][32], ushort_t (*Bs)[64][32],
    f32x4 (&acc)[4][2], int tid)
{
    const int lane = tid & 63, wave = tid >> 6;
    const int wr = wave >> 1, wc = wave & 1;
    const int r0 = tid >> 2, kc = (tid & 3) * 8;
    const int lr = lane & 15, kg = (lane >> 4) * 8;
    gload16(&Ag[(size_t)(m0 + r0) * lda + kc], &As[0][r0][kc]);
    gload16(&Ag[(size_t)(m0 + r0 + 64) * lda + kc], &As[0][r0 + 64][kc]);
    gload16(&Bg[(size_t)(n0 + r0) * ldb + kc], &Bs[0][r0][kc]);
    __syncthreads();
    int cur = 0;
    for (int kt = 0; kt < nkt; kt++) {
        if (kt + 1 < nkt) {
            const int k0 = (kt + 1) * 32;
            gload16(&Ag[(size_t)(m0 + r0) * lda + k0 + kc], &As[cur ^ 1][r0][kc]);
            gload16(&Ag[(size_t)(m0 + r0 + 64) * lda + k0 + kc], &As[cur ^ 1][r0 + 64][kc]);
            gload16(&Bg[(size_t)(n0 + r0) * ldb + k0 + kc], &Bs[cur ^ 1][r0][kc]);
        }
        bf16x8 af[4], bfj[2];
#pragma unroll
        for (int f = 0; f < 4; f++) af[f] = *(const bf16x8*)&As[cur][wr * 64 + f * 16 + lr][kg];
#pragma unroll
        for (int j = 0; j < 2; j++) bfj[j] = *(const bf16x8*)&Bs[cur][wc * 32 + j * 16 + lr][kg];
#pragma unroll
        for (int i = 0; i < 4; i++)
#pragma unroll
            for (int j = 0; j < 2; j++)
                acc[i][j] = __builtin_amdgcn_mfma_f32_16x16x32_bf16(af[i], bfj[j], acc[i][j], 0, 0, 0);
        __syncthreads();
        cur ^= 1;
    }
}

// ---- 128(M)x64(N)-tile i8 MFMA loop, BK=64 (mfma_i32_16x16x64_i8), dbuf.
__device__ __forceinline__ void loop_i8_128x64(
    const u8* __restrict__ Ag, size_t lda,
    const u8* __restrict__ Bg, size_t ldb,
    int m0, int n0, int nkt,
    u8 (*As)[128][64], u8 (*Bs)[64][64],
    i32x4 (&acc)[4][2], int tid)
{
    const int lane = tid & 63, wave = tid >> 6;
    const int wr = wave >> 1, wc = wave & 1;
    const int r0 = tid >> 2, kc = (tid & 3) * 16;
    const int lr = lane & 15, kg = (lane >> 4) * 16;
    gload16(&Ag[(size_t)(m0 + r0) * lda + kc], &As[0][r0][kc]);
    gload16(&Ag[(size_t)(m0 + r0 + 64) * lda + kc], &As[0][r0 + 64][kc]);
    gload16(&Bg[(size_t)(n0 + r0) * ldb + kc], &Bs[0][r0][kc]);
    __syncthreads();
    int cur = 0;
    for (int kt = 0; kt < nkt; kt++) {
        if (kt + 1 < nkt) {
            const int k0 = (kt + 1) * 64;
            gload16(&Ag[(size_t)(m0 + r0) * lda + k0 + kc], &As[cur ^ 1][r0][kc]);
            gload16(&Ag[(size_t)(m0 + r0 + 64) * lda + k0 + kc], &As[cur ^ 1][r0 + 64][kc]);
            gload16(&Bg[(size_t)(n0 + r0) * ldb + k0 + kc], &Bs[cur ^ 1][r0][kc]);
        }
        i32x4 af[4], bfj[2];
#pragma unroll
        for (int f = 0; f < 4; f++) af[f] = *(const i32x4*)&As[cur][wr * 64 + f * 16 + lr][kg];
#pragma unroll
        for (int j = 0; j < 2; j++) bfj[j] = *(const i32x4*)&Bs[cur][wc * 32 + j * 16 + lr][kg];
#pragma unroll
        for (int i = 0; i < 4; i++)
#pragma unroll
            for (int j = 0; j < 2; j++)
                acc[i][j] = __builtin_amdgcn_mfma_i32_16x16x64_i8(af[i], bfj[j], acc[i][j], 0, 0, 0);
        __syncthreads();
        cur ^= 1;
    }
}

// K1 (fused colsum + transpose): per (n0,t0) 32x32 tile, loop over b:
//   xT[b][n][t] = bf16(x[b][t][n]);  xsumT[t][n] = sum_b x;  ssq[n] += sum_t xsum^2
__global__ __launch_bounds__(256) void k_xts(const float* __restrict__ x,
                                             ushort_t* __restrict__ xT,
                                             float* __restrict__ xsumT,
                                             float* __restrict__ ssq) {
    __shared__ float tile[32][33];
    __shared__ float ssqp[32];
    const int n0 = blockIdx.x * 32, t0 = blockIdx.y * 32;
    const int tid = threadIdx.x;
    const int r = tid >> 3, c4 = (tid & 7) * 4;
    if (tid < 32) ssqp[tid] = 0.f;
    float4 acc = {0.f, 0.f, 0.f, 0.f};
    for (int b = 0; b < BB; b++) {
        const float4 v = *(const float4*)&x[(size_t)((b * TT) + t0 + r) * NN + n0 + c4];
        acc.x += v.x; acc.y += v.y; acc.z += v.z; acc.w += v.w;
        __syncthreads();  // previous iter's readers done
        tile[r][c4 + 0] = v.x; tile[r][c4 + 1] = v.y;
        tile[r][c4 + 2] = v.z; tile[r][c4 + 3] = v.w;
        __syncthreads();
        ushort4 o;
        o.x = f2bf(tile[c4 + 0][r]); o.y = f2bf(tile[c4 + 1][r]);
        o.z = f2bf(tile[c4 + 2][r]); o.w = f2bf(tile[c4 + 3][r]);
        *(ushort4*)&xT[(size_t)(b * NN + n0 + r) * TT + t0 + c4] = o;
    }
    *(float4*)&xsumT[(size_t)(t0 + r) * NN + n0 + c4] = acc;
    atomicAdd(&ssqp[c4 + 0], acc.x * acc.x);
    atomicAdd(&ssqp[c4 + 1], acc.y * acc.y);
    atomicAdd(&ssqp[c4 + 2], acc.z * acc.z);
    atomicAdd(&ssqp[c4 + 3], acc.w * acc.w);
    __syncthreads();
    if (tid < 32) atomicAdd(&ssq[n0 + tid], ssqp[tid]);
}

// K2: sim GEMM (fp32, K=256, 64x64 tile, dbuf 2-phase) + gumbel comparator -> adjb (u8)
__global__ __launch_bounds__(256) void k_adj(const float* __restrict__ A,
                                             const float* __restrict__ ssq,
                                             const float* __restrict__ gumbel,
                                             u8* __restrict__ adjb) {
    __shared__ __align__(16) float As[2][32][64];
    __shared__ __align__(16) float Bs[2][32][64];
    const int m0 = blockIdx.y * 64, n0 = blockIdx.x * 64;
    const int tid = threadIdx.x;
    const int tx = tid & 15, ty = tid >> 4;
    const int sr = tid >> 4, sc = (tid & 15) * 4;
    float acc[4][4];
#pragma unroll
    for (int i = 0; i < 4; i++)
#pragma unroll
        for (int j = 0; j < 4; j++) acc[i][j] = 0.f;
    gload16(&A[(size_t)sr * NN + m0 + sc], &As[0][sr][sc]);
    gload16(&A[(size_t)sr * NN + n0 + sc], &Bs[0][sr][sc]);
    gload16(&A[(size_t)(sr + 16) * NN + m0 + sc], &As[0][sr + 16][sc]);
    gload16(&A[(size_t)(sr + 16) * NN + n0 + sc], &Bs[0][sr + 16][sc]);
    __syncthreads();
    int cur = 0;
    for (int kt = 0; kt < 8; kt++) {
        if (kt + 1 < 8) {
            const int k0 = (kt + 1) * 32;
            gload16(&A[(size_t)(k0 + sr) * NN + m0 + sc], &As[cur ^ 1][sr][sc]);
            gload16(&A[(size_t)(k0 + sr) * NN + n0 + sc], &Bs[cur ^ 1][sr][sc]);
            gload16(&A[(size_t)(k0 + sr + 16) * NN + m0 + sc], &As[cur ^ 1][sr + 16][sc]);
            gload16(&A[(size_t)(k0 + sr + 16) * NN + n0 + sc], &Bs[cur ^ 1][sr + 16][sc]);
        }
#pragma unroll 16
        for (int kk = 0; kk < 32; kk++) {
            float4 a = *(const float4*)&As[cur][kk][ty * 4];
            float4 b = *(const float4*)&Bs[cur][kk][tx * 4];
            const float av[4] = {a.x, a.y, a.z, a.w};
            const float bv[4] = {b.x, b.y, b.z, b.w};
#pragma unroll
            for (int i = 0; i < 4; i++)
#pragma unroll
                for (int j = 0; j < 4; j++) acc[i][j] = fmaf(av[i], bv[j], acc[i][j]);
        }
        __syncthreads();
        cur ^= 1;
    }
    float invi[4], invj[4];
#pragma unroll
    for (int i = 0; i < 4; i++) {
        const float si = ssq[m0 + ty * 4 + i];
        invi[i] = (si > 0.f) ? rsqrtf(si) : 0.f;
        const float sj = ssq[n0 + tx * 4 + i];
        invj[i] = (sj > 0.f) ? rsqrtf(sj) : 0.f;
    }
#pragma unroll
    for (int i = 0; i < 4; i++) {
        const int gi = m0 + ty * 4 + i;
        const size_t rowb = (size_t)gi * NN + n0 + tx * 4;
#pragma unroll
        for (int j = 0; j < 4; j++) {
            const float dot = acc[i][j] * invi[i] * invj[j];
            const float2 g = *(const float2*)&gumbel[2 * (rowb + j)];
            adjb[rowb + j] = (dot > g.y - g.x) ? (u8)1 : (u8)0;
        }
    }
}

// K3: nmask = adj | adjT | I  (u8 0/1)
__global__ __launch_bounds__(256) void k_nmask(const u8* __restrict__ adjb,
                                               u8* __restrict__ nm) {
    __shared__ u8 tt[32][33];
    const int J = blockIdx.x * 32, I = blockIdx.y * 32;
    const int c = threadIdx.x & 31, r0 = threadIdx.x >> 5;
#pragma unroll
    for (int r = r0; r < 32; r += 8) tt[r][c] = adjb[(size_t)(J + r) * NN + I + c];
    __syncthreads();
#pragma unroll
    for (int r = r0; r < 32; r += 8) {
        const int gi = I + r, gj = J + c;
        const bool on = (gi == gj) || adjb[(size_t)gi * NN + gj] || tt[c][r];
        nm[(size_t)gi * NN + gj] = on ? (u8)1 : (u8)0;
    }
}

// K4: common = nmask @ nmask (i8 MFMA, integer-exact), fused W + deg partials
__global__ __launch_bounds__(256) void k_commonW(const u8* __restrict__ nm,
                                                 const u8* __restrict__ adjb,
                                                 float* __restrict__ W,
                                                 float* __restrict__ deg) {
    __shared__ __align__(16) u8 As[2][128][64];
    __shared__ __align__(16) u8 Bs[2][64][64];
    const int m0 = blockIdx.y * 128, n0 = blockIdx.x * 64;
    const int tid = threadIdx.x;
    const int lane = tid & 63, wave = tid >> 6;
    const int wr = wave >> 1, wc = wave & 1;
    i32x4 acc[4][2];
#pragma unroll
    for (int i = 0; i < 4; i++)
#pragma unroll
        for (int j = 0; j < 2; j++) acc[i][j] = (i32x4){0, 0, 0, 0};
    loop_i8_128x64(nm, NN, nm, NN, m0, n0, NN / 64, As, Bs, acc, tid);
    const int lr = lane & 15, rg = (lane >> 4) * 4;
#pragma unroll
    for (int j = 0; j < 2; j++) {
        const int gj = n0 + wc * 32 + j * 16 + lr;
        float psum = 0.f;
#pragma unroll
        for (int i = 0; i < 4; i++)
#pragma unroll
            for (int r = 0; r < 4; r++) {
                const int gi = m0 + wr * 64 + i * 16 + rg + r;
                const int cv = acc[i][j][r];
                const size_t fl = (size_t)gi * NN + gj;
                const float cf = (float)cv;
                const float wv = (cv > 1 && adjb[fl]) ? cf * cf : 0.f;
                W[fl] = wv;
                psum += wv;
            }
        atomicAdd(&deg[gj], psum);
    }
}

// K5: Wtn[d][s] = bf16( dinv[s] * W[s][d] * dinv[d] )
__global__ __launch_bounds__(256) void k_wtn(const float* __restrict__ W,
                                             const float* __restrict__ deg,
                                             ushort_t* __restrict__ Wtn) {
    __shared__ float tt[64][65];
    const int S0 = blockIdx.x * 64, D0 = blockIdx.y * 64;
    const int c = threadIdx.x & 63, r0 = threadIdx.x >> 6;
#pragma unroll
    for (int r = r0; r < 64; r += 4) tt[r][c] = W[(size_t)(S0 + r) * NN + D0 + c];
    __syncthreads();
    const float dgs = deg[S0 + c];
    const float ds = (dgs > 0.f) ? rsqrtf(dgs) : 0.f;
#pragma unroll
    for (int r = r0; r < 64; r += 4) {
        const int d = D0 + r;
        const float dgd = deg[d];
        const float dd = (dgd > 0.f) ? rsqrtf(dgd) : 0.f;
        Wtn[(size_t)d * NN + S0 + c] = f2bf(tt[c][r] * ds * dd);
    }
}

// K7: wT[o][t] = bf16(w[t][o])
__global__ __launch_bounds__(256) void k_wt(const float* __restrict__ w,
                                            ushort_t* __restrict__ wT) {
    __shared__ float tile[64][65];
    const int t0 = blockIdx.y * 64, o0 = blockIdx.x * 64;
    const int c = threadIdx.x & 63, r0 = threadIdx.x >> 6;
#pragma unroll
    for (int r = r0; r < 64; r += 4)
        tile[r][c] = w[(size_t)(t0 + r) * TT + o0 + c];
    __syncthreads();
#pragma unroll
    for (int r = r0; r < 64; r += 4)
        wT[(size_t)(o0 + r) * TT + t0 + c] = f2bf(tile[c][r]);
}

// K8: xwT[b][o][n] = sum_t wT[o][t] * xT[b][n][t]  (bf16 MFMA 128x64)
__global__ __launch_bounds__(256) void k_xw(const ushort_t* __restrict__ wT,
                                            const ushort_t* __restrict__ xT,
                                            ushort_t* __restrict__ xwT) {
    __shared__ __align__(16) ushort_t As[2][128][32];
    __shared__ __align__(16) ushort_t Bs[2][64][32];
    const int b = blockIdx.z;
    const ushort_t* __restrict__ Bg = xT + (size_t)b * NN * TT;
    const int m0 = blockIdx.y * 128, n0 = blockIdx.x * 64;
    const int tid = threadIdx.x;
    const int lane = tid & 63, wave = tid >> 6;
    const int wr = wave >> 1, wc = wave & 1;
    f32x4 acc[4][2];
#pragma unroll
    for (int i = 0; i < 4; i++)
#pragma unroll
        for (int j = 0; j < 2; j++) acc[i][j] = (f32x4){0.f, 0.f, 0.f, 0.f};
    loop_bf16_128x64(wT, TT, Bg, TT, m0, n0, TT / 32, As, Bs, acc, tid);
    const int lr = lane & 15, rg = (lane >> 4) * 4;
#pragma unroll
    for (int i = 0; i < 4; i++)
#pragma unroll
        for (int j = 0; j < 2; j++)
#pragma unroll
            for (int r = 0; r < 4; r++) {
                const int o = m0 + wr * 64 + i * 16 + rg + r;
                const int n = n0 + wc * 32 + j * 16 + lr;
                xwT[((size_t)b * TT + o) * NN + n] = f2bf(acc[i][j][r]);
            }
}

// K9: out[bt][d] = sum_s xwT[bt][s] * Wtn[d][s] + bias[bt%T]  (bf16 MFMA 128x64)
__global__ __launch_bounds__(256) void k_out(const ushort_t* __restrict__ xwT,
                                             const ushort_t* __restrict__ Wtn,
                                             const float* __restrict__ bias,
                                             float* __restrict__ out) {
    __shared__ __align__(16) ushort_t As[2][128][32];
    __shared__ __align__(16) ushort_t Bs[2][64][32];
    const int m0 = blockIdx.y * 128, n0 = blockIdx.x * 64;
    const int tid = threadIdx.x;
    const int lane = tid & 63, wave = tid >> 6;
    const int wr = wave >> 1, wc = wave & 1;
    f32x4 acc[4][2];
#pragma unroll
    for (int i = 0; i < 4; i++)
#pragma unroll
        for (int j = 0; j < 2; j++) acc[i][j] = (f32x4){0.f, 0.f, 0.f, 0.f};
    loop_bf16_128x64(xwT, NN, Wtn, NN, m0, n0, NN / 32, As, Bs, acc, tid);
    const int lr = lane & 15, rg = (lane >> 4) * 4;
#pragma unroll
    for (int i = 0; i < 4; i++)
#pragma unroll
        for (int j = 0; j < 2; j++)
#pragma unroll
            for (int r = 0; r < 4; r++) {
                const int gm = m0 + wr * 64 + i * 16 + rg + r;
                const int gd = n0 + wc * 32 + j * 16 + lr;
                out[(size_t)gm * NN + gd] = acc[i][j][r] + bias[gm & (TT - 1)];
            }
}

extern "C" void kernel_launch(void* const* d_in, const int* in_sizes, int n_in,
                              void* d_out, int out_size, void* d_ws, size_t ws_size,
                              hipStream_t stream) {
    const float* x      = (const float*)d_in[0];
    const float* w      = (const float*)d_in[1];
    const float* bias   = (const float*)d_in[2];
    const float* gumbel = (const float*)d_in[3];
    float* out = (float*)d_out;

    char* ws = (char*)d_ws;
    float*    xsumT = (float*)(ws + 0);              //  2 MB [T][N] f32
    float*    ssq   = (float*)(ws + 2097152);        //  8 KB [N]
    float*    deg   = (float*)(ws + 2105344);        //  8 KB [N]
    u8*       adjb  = (u8*)(ws + 2113536);           //  4 MB [N][N] u8
    u8*       nm    = (u8*)(ws + 6307840);           //  4 MB [N][N] u8
    float*    W     = (float*)(ws + 10502144);       // 16 MB [N][N] f32
    ushort_t* xwT   = (ushort_t*)(ws + 10502144);    // 16 MB [B*T][N] bf16 (aliases W, dead after k_wtn)
    ushort_t* Wtn   = (ushort_t*)(ws + 27279360);    //  8 MB [N][N] bf16 (transposed Wn)
    ushort_t* xT    = (ushort_t*)(ws + 35667968);    // 16 MB [B][N][T] bf16
    ushort_t* wT    = (ushort_t*)(ws + 52445184);    // 128 KB [T][T] bf16

    hipMemsetAsync(ws + 2097152, 0, 16384, stream);  // zero ssq + deg

    k_xts    <<<dim3(NN / 32, TT / 32), 256, 0, stream>>>(x, xT, xsumT, ssq);
    k_adj    <<<dim3(32, 32),           256, 0, stream>>>(xsumT, ssq, gumbel, adjb);
    k_nmask  <<<dim3(64, 64),           256, 0, stream>>>(adjb, nm);
    k_commonW<<<dim3(NN / 64, NN / 128),256, 0, stream>>>(nm, adjb, W, deg);
    k_wtn    <<<dim3(32, 32),           256, 0, stream>>>(W, deg, Wtn);
    k_wt     <<<dim3(4, 4),             256, 0, stream>>>(w, wT);
    k_xw     <<<dim3(NN / 64, TT / 128, BB), 256, 0, stream>>>(wT, xT, xwT);
    k_out    <<<dim3(NN / 64, (BB * TT) / 128), 256, 0, stream>>>(xwT, Wtn, bias, out);
}

// Round 8
// 275.649 us; speedup vs baseline: 1.1280x; 1.0205x over previous
//
#include <hip/hip_runtime.h>

#define NN 2048
#define BB 16
#define TT 256

typedef unsigned short ushort_t;
typedef unsigned char u8;
typedef short bf16x8 __attribute__((ext_vector_type(8)));
typedef float f32x4 __attribute__((ext_vector_type(4)));
typedef int i32x4 __attribute__((ext_vector_type(4)));

__device__ __forceinline__ ushort_t f2bf(float f) {
    unsigned u = __float_as_uint(f);
    return (ushort_t)((u + 0x7FFFu + ((u >> 16) & 1u)) >> 16);  // RNE
}

// async global->LDS, 16B per lane; LDS dest must be wave-uniform-base + lane*16
__device__ __forceinline__ void gload16(const void* g, void* l) {
    __builtin_amdgcn_global_load_lds((const __attribute__((address_space(1))) unsigned int*)g,
                                     (__attribute__((address_space(3))) unsigned int*)l,
                                     16, 0, 0);
}

// raw barrier with compiler memory fence (ds_reads must not hoist above it:
// other waves' staged data is only guaranteed complete past this point)
#define SBAR() asm volatile("s_barrier" ::: "memory")

// ---- 128x128-tile bf16 MFMA loop, BK=32, TRIPLE-buffered, counted vmcnt.
// Per step: vmcnt(4) waits only for tile-kt's 4 loads (issued 2 steps ago);
// tile kt+1's 4 stay in flight across the barrier (T4: never drain to 0).
__device__ __forceinline__ void mfma3_bf16_128(
    const ushort_t* __restrict__ Ag, size_t lda,
    const ushort_t* __restrict__ Bg, size_t ldb,
    int m0, int n0, int nkt,
    ushort_t (*As)[128][32], ushort_t (*Bs)[128][32],
    f32x4 (&acc)[4][4], int tid)
{
    const int lane = tid & 63, wave = tid >> 6;
    const int wr = wave >> 1, wc = wave & 1;
    const int r0 = tid >> 2, kc = (tid & 3) * 8;
    const int lr = lane & 15, kg = (lane >> 4) * 8;
#define STAGE_BF(kt, buf) { \
        const int k0_ = (kt) * 32; \
        gload16(&Ag[(size_t)(m0 + r0) * lda + k0_ + kc], &As[buf][r0][kc]); \
        gload16(&Ag[(size_t)(m0 + r0 + 64) * lda + k0_ + kc], &As[buf][r0 + 64][kc]); \
        gload16(&Bg[(size_t)(n0 + r0) * ldb + k0_ + kc], &Bs[buf][r0][kc]); \
        gload16(&Bg[(size_t)(n0 + r0 + 64) * ldb + k0_ + kc], &Bs[buf][r0 + 64][kc]); \
    }
    STAGE_BF(0, 0);
    STAGE_BF(1, 1);
    for (int kt = 0; kt < nkt; kt++) {
        if (kt + 1 < nkt) asm volatile("s_waitcnt vmcnt(4)" ::: "memory");
        else              asm volatile("s_waitcnt vmcnt(0)" ::: "memory");
        SBAR();
        if (kt + 2 < nkt) STAGE_BF(kt + 2, (kt + 2) % 3);
        const int cur = kt % 3;
        bf16x8 af[4], bfj[4];
#pragma unroll
        for (int f = 0; f < 4; f++) {
            af[f]  = *(const bf16x8*)&As[cur][wr * 64 + f * 16 + lr][kg];
            bfj[f] = *(const bf16x8*)&Bs[cur][wc * 64 + f * 16 + lr][kg];
        }
#pragma unroll
        for (int i = 0; i < 4; i++)
#pragma unroll
            for (int j = 0; j < 4; j++)
                acc[i][j] = __builtin_amdgcn_mfma_f32_16x16x32_bf16(af[i], bfj[j], acc[i][j], 0, 0, 0);
    }
#undef STAGE_BF
}

// ---- 128(M)x64(N)-tile i8 MFMA loop, BK=64, TRIPLE-buffered, counted vmcnt (3 loads/step).
__device__ __forceinline__ void mfma3_i8_128x64(
    const u8* __restrict__ Ag, size_t lda,
    const u8* __restrict__ Bg, size_t ldb,
    int m0, int n0, int nkt,
    u8 (*As)[128][64], u8 (*Bs)[64][64],
    i32x4 (&acc)[4][2], int tid)
{
    const int lane = tid & 63, wave = tid >> 6;
    const int wr = wave >> 1, wc = wave & 1;
    const int r0 = tid >> 2, kc = (tid & 3) * 16;
    const int lr = lane & 15, kg = (lane >> 4) * 16;
#define STAGE_I8(kt, buf) { \
        const int k0_ = (kt) * 64; \
        gload16(&Ag[(size_t)(m0 + r0) * lda + k0_ + kc], &As[buf][r0][kc]); \
        gload16(&Ag[(size_t)(m0 + r0 + 64) * lda + k0_ + kc], &As[buf][r0 + 64][kc]); \
        gload16(&Bg[(size_t)(n0 + r0) * ldb + k0_ + kc], &Bs[buf][r0][kc]); \
    }
    STAGE_I8(0, 0);
    STAGE_I8(1, 1);
    for (int kt = 0; kt < nkt; kt++) {
        if (kt + 1 < nkt) asm volatile("s_waitcnt vmcnt(3)" ::: "memory");
        else              asm volatile("s_waitcnt vmcnt(0)" ::: "memory");
        SBAR();
        if (kt + 2 < nkt) STAGE_I8(kt + 2, (kt + 2) % 3);
        const int cur = kt % 3;
        i32x4 af[4], bfj[2];
#pragma unroll
        for (int f = 0; f < 4; f++) af[f] = *(const i32x4*)&As[cur][wr * 64 + f * 16 + lr][kg];
#pragma unroll
        for (int j = 0; j < 2; j++) bfj[j] = *(const i32x4*)&Bs[cur][wc * 32 + j * 16 + lr][kg];
#pragma unroll
        for (int i = 0; i < 4; i++)
#pragma unroll
            for (int j = 0; j < 2; j++)
                acc[i][j] = __builtin_amdgcn_mfma_i32_16x16x64_i8(af[i], bfj[j], acc[i][j], 0, 0, 0);
    }
#undef STAGE_I8
}

// K1 (fused colsum + transpose): per (n0,t0) 32x32 tile, loop over b:
//   xT[b][n][t] = bf16(x[b][t][n]);  xsumT[t][n] = sum_b x;  ssq[n] += sum_t xsum^2
__global__ __launch_bounds__(256) void k_xts(const float* __restrict__ x,
                                             ushort_t* __restrict__ xT,
                                             float* __restrict__ xsumT,
                                             float* __restrict__ ssq) {
    __shared__ float tile[32][33];
    __shared__ float ssqp[32];
    const int n0 = blockIdx.x * 32, t0 = blockIdx.y * 32;
    const int tid = threadIdx.x;
    const int r = tid >> 3, c4 = (tid & 7) * 4;
    if (tid < 32) ssqp[tid] = 0.f;
    float4 acc = {0.f, 0.f, 0.f, 0.f};
    for (int b = 0; b < BB; b++) {
        const float4 v = *(const float4*)&x[(size_t)((b * TT) + t0 + r) * NN + n0 + c4];
        acc.x += v.x; acc.y += v.y; acc.z += v.z; acc.w += v.w;
        __syncthreads();  // previous iter's readers done
        tile[r][c4 + 0] = v.x; tile[r][c4 + 1] = v.y;
        tile[r][c4 + 2] = v.z; tile[r][c4 + 3] = v.w;
        __syncthreads();
        ushort4 o;
        o.x = f2bf(tile[c4 + 0][r]); o.y = f2bf(tile[c4 + 1][r]);
        o.z = f2bf(tile[c4 + 2][r]); o.w = f2bf(tile[c4 + 3][r]);
        *(ushort4*)&xT[(size_t)(b * NN + n0 + r) * TT + t0 + c4] = o;
    }
    *(float4*)&xsumT[(size_t)(t0 + r) * NN + n0 + c4] = acc;
    atomicAdd(&ssqp[c4 + 0], acc.x * acc.x);
    atomicAdd(&ssqp[c4 + 1], acc.y * acc.y);
    atomicAdd(&ssqp[c4 + 2], acc.z * acc.z);
    atomicAdd(&ssqp[c4 + 3], acc.w * acc.w);
    __syncthreads();
    if (tid < 32) atomicAdd(&ssq[n0 + tid], ssqp[tid]);
}

// K2: sim GEMM (fp32, K=256, 64x64 tile, dbuf 2-phase) + gumbel comparator -> adjb (u8)
__global__ __launch_bounds__(256) void k_adj(const float* __restrict__ A,
                                             const float* __restrict__ ssq,
                                             const float* __restrict__ gumbel,
                                             u8* __restrict__ adjb) {
    __shared__ __align__(16) float As[2][32][64];
    __shared__ __align__(16) float Bs[2][32][64];
    const int m0 = blockIdx.y * 64, n0 = blockIdx.x * 64;
    const int tid = threadIdx.x;
    const int tx = tid & 15, ty = tid >> 4;
    const int sr = tid >> 4, sc = (tid & 15) * 4;
    float acc[4][4];
#pragma unroll
    for (int i = 0; i < 4; i++)
#pragma unroll
        for (int j = 0; j < 4; j++) acc[i][j] = 0.f;
    gload16(&A[(size_t)sr * NN + m0 + sc], &As[0][sr][sc]);
    gload16(&A[(size_t)sr * NN + n0 + sc], &Bs[0][sr][sc]);
    gload16(&A[(size_t)(sr + 16) * NN + m0 + sc], &As[0][sr + 16][sc]);
    gload16(&A[(size_t)(sr + 16) * NN + n0 + sc], &Bs[0][sr + 16][sc]);
    __syncthreads();
    int cur = 0;
    for (int kt = 0; kt < 8; kt++) {
        if (kt + 1 < 8) {
            const int k0 = (kt + 1) * 32;
            gload16(&A[(size_t)(k0 + sr) * NN + m0 + sc], &As[cur ^ 1][sr][sc]);
            gload16(&A[(size_t)(k0 + sr) * NN + n0 + sc], &Bs[cur ^ 1][sr][sc]);
            gload16(&A[(size_t)(k0 + sr + 16) * NN + m0 + sc], &As[cur ^ 1][sr + 16][sc]);
            gload16(&A[(size_t)(k0 + sr + 16) * NN + n0 + sc], &Bs[cur ^ 1][sr + 16][sc]);
        }
#pragma unroll 16
        for (int kk = 0; kk < 32; kk++) {
            float4 a = *(const float4*)&As[cur][kk][ty * 4];
            float4 b = *(const float4*)&Bs[cur][kk][tx * 4];
            const float av[4] = {a.x, a.y, a.z, a.w};
            const float bv[4] = {b.x, b.y, b.z, b.w};
#pragma unroll
            for (int i = 0; i < 4; i++)
#pragma unroll
                for (int j = 0; j < 4; j++) acc[i][j] = fmaf(av[i], bv[j], acc[i][j]);
        }
        __syncthreads();
        cur ^= 1;
    }
    float invi[4], invj[4];
#pragma unroll
    for (int i = 0; i < 4; i++) {
        const float si = ssq[m0 + ty * 4 + i];
        invi[i] = (si > 0.f) ? rsqrtf(si) : 0.f;
        const float sj = ssq[n0 + tx * 4 + i];
        invj[i] = (sj > 0.f) ? rsqrtf(sj) : 0.f;
    }
#pragma unroll
    for (int i = 0; i < 4; i++) {
        const int gi = m0 + ty * 4 + i;
        const size_t rowb = (size_t)gi * NN + n0 + tx * 4;
#pragma unroll
        for (int j = 0; j < 4; j++) {
            const float dot = acc[i][j] * invi[i] * invj[j];
            const float2 g = *(const float2*)&gumbel[2 * (rowb + j)];
            adjb[rowb + j] = (dot > g.y - g.x) ? (u8)1 : (u8)0;
        }
    }
}

// K3: nmask = adj | adjT | I  (u8 0/1)
__global__ __launch_bounds__(256) void k_nmask(const u8* __restrict__ adjb,
                                               u8* __restrict__ nm) {
    __shared__ u8 tt[32][33];
    const int J = blockIdx.x * 32, I = blockIdx.y * 32;
    const int c = threadIdx.x & 31, r0 = threadIdx.x >> 5;
#pragma unroll
    for (int r = r0; r < 32; r += 8) tt[r][c] = adjb[(size_t)(J + r) * NN + I + c];
    __syncthreads();
#pragma unroll
    for (int r = r0; r < 32; r += 8) {
        const int gi = I + r, gj = J + c;
        const bool on = (gi == gj) || adjb[(size_t)gi * NN + gj] || tt[c][r];
        nm[(size_t)gi * NN + gj] = on ? (u8)1 : (u8)0;
    }
}

// K4: common = nmask @ nmask (i8 MFMA, integer-exact), fused W + deg partials
__global__ __launch_bounds__(256) void k_commonW(const u8* __restrict__ nm,
                                                 const u8* __restrict__ adjb,
                                                 float* __restrict__ W,
                                                 float* __restrict__ deg) {
    __shared__ __align__(16) u8 As[3][128][64];
    __shared__ __align__(16) u8 Bs[3][64][64];
    const int m0 = blockIdx.y * 128, n0 = blockIdx.x * 64;
    const int tid = threadIdx.x;
    const int lane = tid & 63, wave = tid >> 6;
    const int wr = wave >> 1, wc = wave & 1;
    i32x4 acc[4][2];
#pragma unroll
    for (int i = 0; i < 4; i++)
#pragma unroll
        for (int j = 0; j < 2; j++) acc[i][j] = (i32x4){0, 0, 0, 0};
    mfma3_i8_128x64(nm, NN, nm, NN, m0, n0, NN / 64, As, Bs, acc, tid);
    const int lr = lane & 15, rg = (lane >> 4) * 4;
#pragma unroll
    for (int j = 0; j < 2; j++) {
        const int gj = n0 + wc * 32 + j * 16 + lr;
        float psum = 0.f;
#pragma unroll
        for (int i = 0; i < 4; i++)
#pragma unroll
            for (int r = 0; r < 4; r++) {
                const int gi = m0 + wr * 64 + i * 16 + rg + r;
                const int cv = acc[i][j][r];
                const size_t fl = (size_t)gi * NN + gj;
                const float cf = (float)cv;
                const float wv = (cv > 1 && adjb[fl]) ? cf * cf : 0.f;
                W[fl] = wv;
                psum += wv;
            }
        atomicAdd(&deg[gj], psum);
    }
}

// K5: Wtn[d][s] = bf16( dinv[s] * W[s][d] * dinv[d] )
__global__ __launch_bounds__(256) void k_wtn(const float* __restrict__ W,
                                             const float* __restrict__ deg,
                                             ushort_t* __restrict__ Wtn) {
    __shared__ float tt[64][65];
    const int S0 = blockIdx.x * 64, D0 = blockIdx.y * 64;
    const int c = threadIdx.x & 63, r0 = threadIdx.x >> 6;
#pragma unroll
    for (int r = r0; r < 64; r += 4) tt[r][c] = W[(size_t)(S0 + r) * NN + D0 + c];
    __syncthreads();
    const float dgs = deg[S0 + c];
    const float ds = (dgs > 0.f) ? rsqrtf(dgs) : 0.f;
#pragma unroll
    for (int r = r0; r < 64; r += 4) {
        const int d = D0 + r;
        const float dgd = deg[d];
        const float dd = (dgd > 0.f) ? rsqrtf(dgd) : 0.f;
        Wtn[(size_t)d * NN + S0 + c] = f2bf(tt[c][r] * ds * dd);
    }
}

// K7: wT[o][t] = bf16(w[t][o])
__global__ __launch_bounds__(256) void k_wt(const float* __restrict__ w,
                                            ushort_t* __restrict__ wT) {
    __shared__ float tile[64][65];
    const int t0 = blockIdx.y * 64, o0 = blockIdx.x * 64;
    const int c = threadIdx.x & 63, r0 = threadIdx.x >> 6;
#pragma unroll
    for (int r = r0; r < 64; r += 4)
        tile[r][c] = w[(size_t)(t0 + r) * TT + o0 + c];
    __syncthreads();
#pragma unroll
    for (int r = r0; r < 64; r += 4)
        wT[(size_t)(o0 + r) * TT + t0 + c] = f2bf(tile[c][r]);
}

// K8: xwT[b][o][n] = sum_t wT[o][t] * xT[b][n][t]  (bf16 MFMA 128x128, triple-buf)
__global__ __launch_bounds__(256) void k_xw(const ushort_t* __restrict__ wT,
                                            const ushort_t* __restrict__ xT,
                                            ushort_t* __restrict__ xwT) {
    __shared__ __align__(16) ushort_t As[3][128][32];
    __shared__ __align__(16) ushort_t Bs[3][128][32];
    const int b = blockIdx.z;
    const ushort_t* __restrict__ Bg = xT + (size_t)b * NN * TT;
    const int m0 = blockIdx.y * 128, n0 = blockIdx.x * 128;
    const int tid = threadIdx.x;
    const int lane = tid & 63, wave = tid >> 6;
    const int wr = wave >> 1, wc = wave & 1;
    f32x4 acc[4][4];
#pragma unroll
    for (int i = 0; i < 4; i++)
#pragma unroll
        for (int j = 0; j < 4; j++) acc[i][j] = (f32x4){0.f, 0.f, 0.f, 0.f};
    mfma3_bf16_128(wT, TT, Bg, TT, m0, n0, TT / 32, As, Bs, acc, tid);
    const int lr = lane & 15, rg = (lane >> 4) * 4;
#pragma unroll
    for (int i = 0; i < 4; i++)
#pragma unroll
        for (int j = 0; j < 4; j++)
#pragma unroll
            for (int r = 0; r < 4; r++) {
                const int o = m0 + wr * 64 + i * 16 + rg + r;
                const int n = n0 + wc * 64 + j * 16 + lr;
                xwT[((size_t)b * TT + o) * NN + n] = f2bf(acc[i][j][r]);
            }
}

// K9: out[bt][d] = sum_s xwT[bt][s] * Wtn[d][s] + bias[bt%T]  (bf16 MFMA 128x128, triple-buf)
__global__ __launch_bounds__(256) void k_out(const ushort_t* __restrict__ xwT,
                                             const ushort_t* __restrict__ Wtn,
                                             const float* __restrict__ bias,
                                             float* __restrict__ out) {
    __shared__ __align__(16) ushort_t As[3][128][32];
    __shared__ __align__(16) ushort_t Bs[3][128][32];
    const int m0 = blockIdx.y * 128, n0 = blockIdx.x * 128;
    const int tid = threadIdx.x;
    const int lane = tid & 63, wave = tid >> 6;
    const int wr = wave >> 1, wc = wave & 1;
    f32x4 acc[4][4];
#pragma unroll
    for (int i = 0; i < 4; i++)
#pragma unroll
        for (int j = 0; j < 4; j++) acc[i][j] = (f32x4){0.f, 0.f, 0.f, 0.f};
    mfma3_bf16_128(xwT, NN, Wtn, NN, m0, n0, NN / 32, As, Bs, acc, tid);
    const int lr = lane & 15, rg = (lane >> 4) * 4;
#pragma unroll
    for (int i = 0; i < 4; i++)
#pragma unroll
        for (int j = 0; j < 4; j++)
#pragma unroll
            for (int r = 0; r < 4; r++) {
                const int gm = m0 + wr * 64 + i * 16 + rg + r;  // bt
                const int gd = n0 + wc * 64 + j * 16 + lr;      // node d
                out[(size_t)gm * NN + gd] = acc[i][j][r] + bias[gm & (TT - 1)];
            }
}

extern "C" void kernel_launch(void* const* d_in, const int* in_sizes, int n_in,
                              void* d_out, int out_size, void* d_ws, size_t ws_size,
                              hipStream_t stream) {
    const float* x      = (const float*)d_in[0];
    const float* w      = (const float*)d_in[1];
    const float* bias   = (const float*)d_in[2];
    const float* gumbel = (const float*)d_in[3];
    float* out = (float*)d_out;

    char* ws = (char*)d_ws;
    float*    xsumT = (float*)(ws + 0);              //  2 MB [T][N] f32
    float*    ssq   = (float*)(ws + 2097152);        //  8 KB [N]
    float*    deg   = (float*)(ws + 2105344);        //  8 KB [N]
    u8*       adjb  = (u8*)(ws + 2113536);           //  4 MB [N][N] u8
    u8*       nm    = (u8*)(ws + 6307840);           //  4 MB [N][N] u8
    float*    W     = (float*)(ws + 10502144);       // 16 MB [N][N] f32
    ushort_t* xwT   = (ushort_t*)(ws + 10502144);    // 16 MB [B*T][N] bf16 (aliases W, dead after k_wtn)
    ushort_t* Wtn   = (ushort_t*)(ws + 27279360);    //  8 MB [N][N] bf16 (transposed Wn)
    ushort_t* xT    = (ushort_t*)(ws + 35667968);    // 16 MB [B][N][T] bf16
    ushort_t* wT    = (ushort_t*)(ws + 52445184);    // 128 KB [T][T] bf16

    hipMemsetAsync(ws + 2097152, 0, 16384, stream);  // zero ssq + deg

    k_xts    <<<dim3(NN / 32, TT / 32), 256, 0, stream>>>(x, xT, xsumT, ssq);
    k_adj    <<<dim3(32, 32),           256, 0, stream>>>(xsumT, ssq, gumbel, adjb);
    k_nmask  <<<dim3(64, 64),           256, 0, stream>>>(adjb, nm);
    k_commonW<<<dim3(NN / 64, NN / 128),256, 0, stream>>>(nm, adjb, W, deg);
    k_wtn    <<<dim3(32, 32),           256, 0, stream>>>(W, deg, Wtn);
    k_wt     <<<dim3(4, 4),             256, 0, stream>>>(w, wT);
    k_xw     <<<dim3(NN / 128, TT / 128, BB),   256, 0, stream>>>(wT, xT, xwT);
    k_out    <<<dim3(NN / 128, (BB * TT) / 128), 256, 0, stream>>>(xwT, Wtn, bias, out);
}

// Round 9
// 270.222 us; speedup vs baseline: 1.1507x; 1.0201x over previous
//
#include <hip/hip_runtime.h>

#define NN 2048
#define BB 16
#define TT 256

typedef unsigned short ushort_t;
typedef unsigned char u8;
typedef short bf16x8 __attribute__((ext_vector_type(8)));
typedef float f32x4 __attribute__((ext_vector_type(4)));
typedef int i32x4 __attribute__((ext_vector_type(4)));

__device__ __forceinline__ ushort_t f2bf(float f) {
    unsigned u = __float_as_uint(f);
    return (ushort_t)((u + 0x7FFFu + ((u >> 16) & 1u)) >> 16);  // RNE
}

// async global->LDS, 16B per lane; LDS dest must be wave-uniform-base + lane*16
__device__ __forceinline__ void gload16(const void* g, void* l) {
    __builtin_amdgcn_global_load_lds((const __attribute__((address_space(1))) unsigned int*)g,
                                     (__attribute__((address_space(3))) unsigned int*)l,
                                     16, 0, 0);
}

// raw barrier with compiler memory fence
#define SBAR() asm volatile("s_barrier" ::: "memory")

// ---- 128x128-tile bf16 MFMA loop, BK=32, 4-buffer ring, prefetch depth 3.
// Steady state: 12 loads in flight (tiles kt..kt+2); vmcnt(8) retires tile kt only.
__device__ __forceinline__ void mfma4_bf16_128(
    const ushort_t* __restrict__ Ag, size_t lda,
    const ushort_t* __restrict__ Bg, size_t ldb,
    int m0, int n0, int nkt,
    ushort_t (*As)[128][32], ushort_t (*Bs)[128][32],
    f32x4 (&acc)[4][4], int tid)
{
    const int lane = tid & 63, wave = tid >> 6;
    const int wr = wave >> 1, wc = wave & 1;
    const int r0 = tid >> 2, kc = (tid & 3) * 8;
    const int lr = lane & 15, kg = (lane >> 4) * 8;
#define STAGE_BF(kt, buf) { \
        const int k0_ = (kt) * 32; \
        gload16(&Ag[(size_t)(m0 + r0) * lda + k0_ + kc], &As[buf][r0][kc]); \
        gload16(&Ag[(size_t)(m0 + r0 + 64) * lda + k0_ + kc], &As[buf][r0 + 64][kc]); \
        gload16(&Bg[(size_t)(n0 + r0) * ldb + k0_ + kc], &Bs[buf][r0][kc]); \
        gload16(&Bg[(size_t)(n0 + r0 + 64) * ldb + k0_ + kc], &Bs[buf][r0 + 64][kc]); \
    }
    for (int p = 0; p < 3 && p < nkt; p++) STAGE_BF(p, p);
    for (int kt = 0; kt < nkt; kt++) {
        const int rem = nkt - 1 - kt;
        if (rem >= 2)      asm volatile("s_waitcnt vmcnt(8)" ::: "memory");
        else if (rem == 1) asm volatile("s_waitcnt vmcnt(4)" ::: "memory");
        else               asm volatile("s_waitcnt vmcnt(0)" ::: "memory");
        SBAR();
        if (kt + 3 < nkt) STAGE_BF(kt + 3, (kt + 3) & 3);
        const int cur = kt & 3;
        bf16x8 af[4], bfj[4];
#pragma unroll
        for (int f = 0; f < 4; f++) {
            af[f]  = *(const bf16x8*)&As[cur][wr * 64 + f * 16 + lr][kg];
            bfj[f] = *(const bf16x8*)&Bs[cur][wc * 64 + f * 16 + lr][kg];
        }
#pragma unroll
        for (int i = 0; i < 4; i++)
#pragma unroll
            for (int j = 0; j < 4; j++)
                acc[i][j] = __builtin_amdgcn_mfma_f32_16x16x32_bf16(af[i], bfj[j], acc[i][j], 0, 0, 0);
    }
#undef STAGE_BF
}

// ---- 128(M)x64(N)-tile i8 MFMA loop, BK=64, 4-buffer ring, depth 3 (3 loads/step).
__device__ __forceinline__ void mfma4_i8_128x64(
    const u8* __restrict__ Ag, size_t lda,
    const u8* __restrict__ Bg, size_t ldb,
    int m0, int n0, int nkt,
    u8 (*As)[128][64], u8 (*Bs)[64][64],
    i32x4 (&acc)[4][2], int tid)
{
    const int lane = tid & 63, wave = tid >> 6;
    const int wr = wave >> 1, wc = wave & 1;
    const int r0 = tid >> 2, kc = (tid & 3) * 16;
    const int lr = lane & 15, kg = (lane >> 4) * 16;
#define STAGE_I8(kt, buf) { \
        const int k0_ = (kt) * 64; \
        gload16(&Ag[(size_t)(m0 + r0) * lda + k0_ + kc], &As[buf][r0][kc]); \
        gload16(&Ag[(size_t)(m0 + r0 + 64) * lda + k0_ + kc], &As[buf][r0 + 64][kc]); \
        gload16(&Bg[(size_t)(n0 + r0) * ldb + k0_ + kc], &Bs[buf][r0][kc]); \
    }
    for (int p = 0; p < 3 && p < nkt; p++) STAGE_I8(p, p);
    for (int kt = 0; kt < nkt; kt++) {
        const int rem = nkt - 1 - kt;
        if (rem >= 2)      asm volatile("s_waitcnt vmcnt(6)" ::: "memory");
        else if (rem == 1) asm volatile("s_waitcnt vmcnt(3)" ::: "memory");
        else               asm volatile("s_waitcnt vmcnt(0)" ::: "memory");
        SBAR();
        if (kt + 3 < nkt) STAGE_I8(kt + 3, (kt + 3) & 3);
        const int cur = kt & 3;
        i32x4 af[4], bfj[2];
#pragma unroll
        for (int f = 0; f < 4; f++) af[f] = *(const i32x4*)&As[cur][wr * 64 + f * 16 + lr][kg];
#pragma unroll
        for (int j = 0; j < 2; j++) bfj[j] = *(const i32x4*)&Bs[cur][wc * 32 + j * 16 + lr][kg];
#pragma unroll
        for (int i = 0; i < 4; i++)
#pragma unroll
            for (int j = 0; j < 2; j++)
                acc[i][j] = __builtin_amdgcn_mfma_i32_16x16x64_i8(af[i], bfj[j], acc[i][j], 0, 0, 0);
    }
#undef STAGE_I8
}

// K1 (fused colsum + transpose)
__global__ __launch_bounds__(256) void k_xts(const float* __restrict__ x,
                                             ushort_t* __restrict__ xT,
                                             float* __restrict__ xsumT,
                                             float* __restrict__ ssq) {
    __shared__ float tile[32][33];
    __shared__ float ssqp[32];
    const int n0 = blockIdx.x * 32, t0 = blockIdx.y * 32;
    const int tid = threadIdx.x;
    const int r = tid >> 3, c4 = (tid & 7) * 4;
    if (tid < 32) ssqp[tid] = 0.f;
    float4 acc = {0.f, 0.f, 0.f, 0.f};
    for (int b = 0; b < BB; b++) {
        const float4 v = *(const float4*)&x[(size_t)((b * TT) + t0 + r) * NN + n0 + c4];
        acc.x += v.x; acc.y += v.y; acc.z += v.z; acc.w += v.w;
        __syncthreads();
        tile[r][c4 + 0] = v.x; tile[r][c4 + 1] = v.y;
        tile[r][c4 + 2] = v.z; tile[r][c4 + 3] = v.w;
        __syncthreads();
        ushort4 o;
        o.x = f2bf(tile[c4 + 0][r]); o.y = f2bf(tile[c4 + 1][r]);
        o.z = f2bf(tile[c4 + 2][r]); o.w = f2bf(tile[c4 + 3][r]);
        *(ushort4*)&xT[(size_t)(b * NN + n0 + r) * TT + t0 + c4] = o;
    }
    *(float4*)&xsumT[(size_t)(t0 + r) * NN + n0 + c4] = acc;
    atomicAdd(&ssqp[c4 + 0], acc.x * acc.x);
    atomicAdd(&ssqp[c4 + 1], acc.y * acc.y);
    atomicAdd(&ssqp[c4 + 2], acc.z * acc.z);
    atomicAdd(&ssqp[c4 + 3], acc.w * acc.w);
    __syncthreads();
    if (tid < 32) atomicAdd(&ssq[n0 + tid], ssqp[tid]);
}

// K2: sim GEMM (fp32) + gumbel comparator -> adjb (u8)
__global__ __launch_bounds__(256) void k_adj(const float* __restrict__ A,
                                             const float* __restrict__ ssq,
                                             const float* __restrict__ gumbel,
                                             u8* __restrict__ adjb) {
    __shared__ __align__(16) float As[2][32][64];
    __shared__ __align__(16) float Bs[2][32][64];
    const int m0 = blockIdx.y * 64, n0 = blockIdx.x * 64;
    const int tid = threadIdx.x;
    const int tx = tid & 15, ty = tid >> 4;
    const int sr = tid >> 4, sc = (tid & 15) * 4;
    float acc[4][4];
#pragma unroll
    for (int i = 0; i < 4; i++)
#pragma unroll
        for (int j = 0; j < 4; j++) acc[i][j] = 0.f;
    gload16(&A[(size_t)sr * NN + m0 + sc], &As[0][sr][sc]);
    gload16(&A[(size_t)sr * NN + n0 + sc], &Bs[0][sr][sc]);
    gload16(&A[(size_t)(sr + 16) * NN + m0 + sc], &As[0][sr + 16][sc]);
    gload16(&A[(size_t)(sr + 16) * NN + n0 + sc], &Bs[0][sr + 16][sc]);
    __syncthreads();
    int cur = 0;
    for (int kt = 0; kt < 8; kt++) {
        if (kt + 1 < 8) {
            const int k0 = (kt + 1) * 32;
            gload16(&A[(size_t)(k0 + sr) * NN + m0 + sc], &As[cur ^ 1][sr][sc]);
            gload16(&A[(size_t)(k0 + sr) * NN + n0 + sc], &Bs[cur ^ 1][sr][sc]);
            gload16(&A[(size_t)(k0 + sr + 16) * NN + m0 + sc], &As[cur ^ 1][sr + 16][sc]);
            gload16(&A[(size_t)(k0 + sr + 16) * NN + n0 + sc], &Bs[cur ^ 1][sr + 16][sc]);
        }
#pragma unroll 16
        for (int kk = 0; kk < 32; kk++) {
            float4 a = *(const float4*)&As[cur][kk][ty * 4];
            float4 b = *(const float4*)&Bs[cur][kk][tx * 4];
            const float av[4] = {a.x, a.y, a.z, a.w};
            const float bv[4] = {b.x, b.y, b.z, b.w};
#pragma unroll
            for (int i = 0; i < 4; i++)
#pragma unroll
                for (int j = 0; j < 4; j++) acc[i][j] = fmaf(av[i], bv[j], acc[i][j]);
        }
        __syncthreads();
        cur ^= 1;
    }
    float invi[4], invj[4];
#pragma unroll
    for (int i = 0; i < 4; i++) {
        const float si = ssq[m0 + ty * 4 + i];
        invi[i] = (si > 0.f) ? rsqrtf(si) : 0.f;
        const float sj = ssq[n0 + tx * 4 + i];
        invj[i] = (sj > 0.f) ? rsqrtf(sj) : 0.f;
    }
#pragma unroll
    for (int i = 0; i < 4; i++) {
        const int gi = m0 + ty * 4 + i;
        const size_t rowb = (size_t)gi * NN + n0 + tx * 4;
#pragma unroll
        for (int j = 0; j < 4; j++) {
            const float dot = acc[i][j] * invi[i] * invj[j];
            const float2 g = *(const float2*)&gumbel[2 * (rowb + j)];
            adjb[rowb + j] = (dot > g.y - g.x) ? (u8)1 : (u8)0;
        }
    }
}

// K3: nmask = adj | adjT | I  (u8 0/1)
__global__ __launch_bounds__(256) void k_nmask(const u8* __restrict__ adjb,
                                               u8* __restrict__ nm) {
    __shared__ u8 tt[32][33];
    const int J = blockIdx.x * 32, I = blockIdx.y * 32;
    const int c = threadIdx.x & 31, r0 = threadIdx.x >> 5;
#pragma unroll
    for (int r = r0; r < 32; r += 8) tt[r][c] = adjb[(size_t)(J + r) * NN + I + c];
    __syncthreads();
#pragma unroll
    for (int r = r0; r < 32; r += 8) {
        const int gi = I + r, gj = J + c;
        const bool on = (gi == gj) || adjb[(size_t)gi * NN + gj] || tt[c][r];
        nm[(size_t)gi * NN + gj] = on ? (u8)1 : (u8)0;
    }
}

// K4: common = nmask @ nmask (i8 MFMA), fused W + deg partials. XCD-chunked blocks.
__global__ __launch_bounds__(256) void k_commonW(const u8* __restrict__ nm,
                                                 const u8* __restrict__ adjb,
                                                 float* __restrict__ W,
                                                 float* __restrict__ deg) {
    __shared__ __align__(16) u8 As[4][128][64];
    __shared__ __align__(16) u8 Bs[4][64][64];
    // XCD swizzle: grid (32 x, 16 y); per-XCD chunk = 16x * 4y (working set ~3 MB < L2)
    const int id = blockIdx.y * 32 + blockIdx.x;
    const int xcd = id & 7, c = id >> 3;
    const int bx = ((xcd & 1) << 4) | (c & 15);
    const int by = ((xcd >> 1) << 2) | (c >> 4);
    const int m0 = by * 128, n0 = bx * 64;
    const int tid = threadIdx.x;
    const int lane = tid & 63, wave = tid >> 6;
    const int wr = wave >> 1, wc = wave & 1;
    i32x4 acc[4][2];
#pragma unroll
    for (int i = 0; i < 4; i++)
#pragma unroll
        for (int j = 0; j < 2; j++) acc[i][j] = (i32x4){0, 0, 0, 0};
    mfma4_i8_128x64(nm, NN, nm, NN, m0, n0, NN / 64, As, Bs, acc, tid);
    const int lr = lane & 15, rg = (lane >> 4) * 4;
#pragma unroll
    for (int j = 0; j < 2; j++) {
        const int gj = n0 + wc * 32 + j * 16 + lr;
        float psum = 0.f;
#pragma unroll
        for (int i = 0; i < 4; i++)
#pragma unroll
            for (int r = 0; r < 4; r++) {
                const int gi = m0 + wr * 64 + i * 16 + rg + r;
                const int cv = acc[i][j][r];
                const size_t fl = (size_t)gi * NN + gj;
                const float cf = (float)cv;
                const float wv = (cv > 1 && adjb[fl]) ? cf * cf : 0.f;
                W[fl] = wv;
                psum += wv;
            }
        atomicAdd(&deg[gj], psum);
    }
}

// K5: Wtn[d][s] = bf16( dinv[s] * W[s][d] * dinv[d] )
__global__ __launch_bounds__(256) void k_wtn(const float* __restrict__ W,
                                             const float* __restrict__ deg,
                                             ushort_t* __restrict__ Wtn) {
    __shared__ float tt[64][65];
    const int S0 = blockIdx.x * 64, D0 = blockIdx.y * 64;
    const int c = threadIdx.x & 63, r0 = threadIdx.x >> 6;
#pragma unroll
    for (int r = r0; r < 64; r += 4) tt[r][c] = W[(size_t)(S0 + r) * NN + D0 + c];
    __syncthreads();
    const float dgs = deg[S0 + c];
    const float ds = (dgs > 0.f) ? rsqrtf(dgs) : 0.f;
#pragma unroll
    for (int r = r0; r < 64; r += 4) {
        const int d = D0 + r;
        const float dgd = deg[d];
        const float dd = (dgd > 0.f) ? rsqrtf(dgd) : 0.f;
        Wtn[(size_t)d * NN + S0 + c] = f2bf(tt[c][r] * ds * dd);
    }
}

// K7: wT[o][t] = bf16(w[t][o])
__global__ __launch_bounds__(256) void k_wt(const float* __restrict__ w,
                                            ushort_t* __restrict__ wT) {
    __shared__ float tile[64][65];
    const int t0 = blockIdx.y * 64, o0 = blockIdx.x * 64;
    const int c = threadIdx.x & 63, r0 = threadIdx.x >> 6;
#pragma unroll
    for (int r = r0; r < 64; r += 4)
        tile[r][c] = w[(size_t)(t0 + r) * TT + o0 + c];
    __syncthreads();
#pragma unroll
    for (int r = r0; r < 64; r += 4)
        wT[(size_t)(o0 + r) * TT + t0 + c] = f2bf(tile[c][r]);
}

// K8: xwT[b][o][n] = sum_t wT[o][t] * xT[b][n][t]  (bf16 MFMA 128x128, 4-buf ring)
__global__ __launch_bounds__(256) void k_xw(const ushort_t* __restrict__ wT,
                                            const ushort_t* __restrict__ xT,
                                            ushort_t* __restrict__ xwT) {
    __shared__ __align__(16) ushort_t As[4][128][32];
    __shared__ __align__(16) ushort_t Bs[4][128][32];
    const int b = blockIdx.z;
    const ushort_t* __restrict__ Bg = xT + (size_t)b * NN * TT;
    const int m0 = blockIdx.y * 128, n0 = blockIdx.x * 128;
    const int tid = threadIdx.x;
    const int lane = tid & 63, wave = tid >> 6;
    const int wr = wave >> 1, wc = wave & 1;
    f32x4 acc[4][4];
#pragma unroll
    for (int i = 0; i < 4; i++)
#pragma unroll
        for (int j = 0; j < 4; j++) acc[i][j] = (f32x4){0.f, 0.f, 0.f, 0.f};
    mfma4_bf16_128(wT, TT, Bg, TT, m0, n0, TT / 32, As, Bs, acc, tid);
    const int lr = lane & 15, rg = (lane >> 4) * 4;
#pragma unroll
    for (int i = 0; i < 4; i++)
#pragma unroll
        for (int j = 0; j < 4; j++)
#pragma unroll
            for (int r = 0; r < 4; r++) {
                const int o = m0 + wr * 64 + i * 16 + rg + r;
                const int n = n0 + wc * 64 + j * 16 + lr;
                xwT[((size_t)b * TT + o) * NN + n] = f2bf(acc[i][j][r]);
            }
}

// K9: out[bt][d] = sum_s xwT[bt][s] * Wtn[d][s] + bias  (bf16 MFMA 128x128, 4-buf, XCD-chunked)
__global__ __launch_bounds__(256) void k_out(const ushort_t* __restrict__ xwT,
                                             const ushort_t* __restrict__ Wtn,
                                             const float* __restrict__ bias,
                                             float* __restrict__ out) {
    __shared__ __align__(16) ushort_t As[4][128][32];
    __shared__ __align__(16) ushort_t Bs[4][128][32];
    // XCD swizzle: grid (16 x, 32 y); per-XCD chunk = 8x * 8y (~8 MB working set)
    const int id = blockIdx.y * 16 + blockIdx.x;
    const int xcd = id & 7, c = id >> 3;
    const int bx = ((xcd & 1) << 3) | (c & 7);
    const int by = ((xcd >> 1) << 3) | (c >> 3);
    const int m0 = by * 128, n0 = bx * 128;
    const int tid = threadIdx.x;
    const int lane = tid & 63, wave = tid >> 6;
    const int wr = wave >> 1, wc = wave & 1;
    f32x4 acc[4][4];
#pragma unroll
    for (int i = 0; i < 4; i++)
#pragma unroll
        for (int j = 0; j < 4; j++) acc[i][j] = (f32x4){0.f, 0.f, 0.f, 0.f};
    mfma4_bf16_128(xwT, NN, Wtn, NN, m0, n0, NN / 32, As, Bs, acc, tid);
    const int lr = lane & 15, rg = (lane >> 4) * 4;
#pragma unroll
    for (int i = 0; i < 4; i++)
#pragma unroll
        for (int j = 0; j < 4; j++)
#pragma unroll
            for (int r = 0; r < 4; r++) {
                const int gm = m0 + wr * 64 + i * 16 + rg + r;  // bt
                const int gd = n0 + wc * 64 + j * 16 + lr;      // node d
                out[(size_t)gm * NN + gd] = acc[i][j][r] + bias[gm & (TT - 1)];
            }
}

extern "C" void kernel_launch(void* const* d_in, const int* in_sizes, int n_in,
                              void* d_out, int out_size, void* d_ws, size_t ws_size,
                              hipStream_t stream) {
    const float* x      = (const float*)d_in[0];
    const float* w      = (const float*)d_in[1];
    const float* bias   = (const float*)d_in[2];
    const float* gumbel = (const float*)d_in[3];
    float* out = (float*)d_out;

    char* ws = (char*)d_ws;
    float*    xsumT = (float*)(ws + 0);              //  2 MB [T][N] f32
    float*    ssq   = (float*)(ws + 2097152);        //  8 KB [N]
    float*    deg   = (float*)(ws + 2105344);        //  8 KB [N]
    u8*       adjb  = (u8*)(ws + 2113536);           //  4 MB [N][N] u8
    u8*       nm    = (u8*)(ws + 6307840);           //  4 MB [N][N] u8
    float*    W     = (float*)(ws + 10502144);       // 16 MB [N][N] f32
    ushort_t* xwT   = (ushort_t*)(ws + 10502144);    // 16 MB [B*T][N] bf16 (aliases W, dead after k_wtn)
    ushort_t* Wtn   = (ushort_t*)(ws + 27279360);    //  8 MB [N][N] bf16 (transposed Wn)
    ushort_t* xT    = (ushort_t*)(ws + 35667968);    // 16 MB [B][N][T] bf16
    ushort_t* wT    = (ushort_t*)(ws + 52445184);    // 128 KB [T][T] bf16

    hipMemsetAsync(ws + 2097152, 0, 16384, stream);  // zero ssq + deg

    k_xts    <<<dim3(NN / 32, TT / 32), 256, 0, stream>>>(x, xT, xsumT, ssq);
    k_adj    <<<dim3(32, 32),           256, 0, stream>>>(xsumT, ssq, gumbel, adjb);
    k_nmask  <<<dim3(64, 64),           256, 0, stream>>>(adjb, nm);
    k_commonW<<<dim3(NN / 64, NN / 128),256, 0, stream>>>(nm, adjb, W, deg);
    k_wtn    <<<dim3(32, 32),           256, 0, stream>>>(W, deg, Wtn);
    k_wt     <<<dim3(4, 4),             256, 0, stream>>>(w, wT);
    k_xw     <<<dim3(NN / 128, TT / 128, BB),   256, 0, stream>>>(wT, xT, xwT);
    k_out    <<<dim3(NN / 128, (BB * TT) / 128), 256, 0, stream>>>(xwT, Wtn, bias, out);
}